// Round 8
// baseline (22210.158 us; speedup 1.0000x reference)
//
#include <hip/hip_runtime.h>
#include <math.h>

#define EMBED 768
#define HEADS 8
#define HDIM  96
#define NEG_MASK (-1.0e30f)

typedef unsigned short u16;
typedef unsigned int   u32;

__device__ __forceinline__ float bf2f(u16 u) {
    return __uint_as_float(((u32)u) << 16);
}
__device__ __forceinline__ u16 f2bf(float f) {
    u32 x = __float_as_uint(f);
    u32 r = (x + 0x7fffu + ((x >> 16) & 1u)) >> 16;
    return (u16)r;
}
__device__ __forceinline__ void unpack2(u32 w, float& lo, float& hi) {
    lo = __uint_as_float(w << 16);
    hi = __uint_as_float(w & 0xffff0000u);
}
__device__ __forceinline__ float wget(const void* p, size_t i, int wf) {
    return wf ? ((const float*)p)[i] : bf2f(((const u16*)p)[i]);
}

// ---------------- detection ----------------
__global__ __launch_bounds__(64) void detect_kernel(const u16* __restrict__ x,
                                                    const int* __restrict__ el,
                                                    const int* __restrict__ usp,
                                                    int* __restrict__ blk) {
    int lane = threadIdx.x;
    int cnt = 0;
    for (int i = lane; i < 4096; i += 64) {
        u32 e = (x[i] >> 7) & 0xFFu;
        if (e >= 0xC0u) cnt++;
    }
#pragma unroll
    for (int off = 32; off > 0; off >>= 1) cnt += __shfl_xor(cnt, off, 64);
    if (lane == 0) {
        blk[0] = (cnt > 32) ? 1 : 0;
        bool i64 = (el[1] == 0) && (el[3] == 0) && (el[5] == 0) && (el[7] == 0);
        for (int b = 0; b < 8; b++) blk[1 + b] = i64 ? el[2 * b] : el[b];
        blk[9] = usp[0];
    }
}

// ---------------- copies ----------------
__global__ void wire_to_f32(const void* __restrict__ in, size_t ioff,
                            float* __restrict__ out, int n,
                            const int* __restrict__ blk) {
    int i = blockIdx.x * blockDim.x + threadIdx.x;
    int wf = blk[0];
    if (i < n) out[i] = wget(in, ioff + (size_t)i, wf);
}
__global__ void wire_copy(const void* __restrict__ in, void* __restrict__ out,
                          int n, const int* __restrict__ blk) {
    int i = blockIdx.x * blockDim.x + threadIdx.x;
    int wf = blk[0];
    if (i < n) {
        if (wf) ((float*)out)[i] = ((const float*)in)[i];
        else    ((u16*)out)[i]   = ((const u16*)in)[i];
    }
}
__global__ void f32_to_out(const float* __restrict__ in, void* __restrict__ out,
                           size_t ooff, int n, const int* __restrict__ blk) {
    int i = blockIdx.x * blockDim.x + threadIdx.x;
    int wf = blk[0];
    if (i < n) {
        if (wf) ((float*)out)[ooff + i] = in[i];
        else    ((u16*)out)[ooff + i]   = f2bf(in[i]);
    }
}

// ---------------- LayerNorm ----------------
__global__ __launch_bounds__(256) void ln_kernel(const void* __restrict__ in,
                                                 size_t ioff, int sel,
                                                 const void* __restrict__ g,
                                                 const void* __restrict__ b,
                                                 u16* __restrict__ out,
                                                 const int* __restrict__ blk) {
    int wf = blk[0];
    int row = blockIdx.x, tid = threadIdx.x;
    size_t base = ioff + (size_t)row * EMBED;
    float v[3];
#pragma unroll
    for (int e = 0; e < 3; e++) {
        size_t idx = base + tid + e * 256;
        v[e] = (sel == 0) ? ((const float*)in)[idx] : wget(in, idx, wf);
    }
    float s = v[0] + v[1] + v[2];
    float q = v[0] * v[0] + v[1] * v[1] + v[2] * v[2];
#pragma unroll
    for (int off = 32; off > 0; off >>= 1) {
        s += __shfl_xor(s, off, 64);
        q += __shfl_xor(q, off, 64);
    }
    __shared__ float sb[8];
    int wid = tid >> 6, lane = tid & 63;
    if (lane == 0) { sb[wid] = s; sb[4 + wid] = q; }
    __syncthreads();
    if (tid == 0) {
        sb[0] = sb[0] + sb[1] + sb[2] + sb[3];
        sb[4] = sb[4] + sb[5] + sb[6] + sb[7];
    }
    __syncthreads();
    float mean = sb[0] * (1.0f / EMBED);
    float var  = sb[4] * (1.0f / EMBED) - mean * mean;
    float rs   = rsqrtf(var + 1e-5f);
    size_t obase = (size_t)row * EMBED;
#pragma unroll
    for (int e = 0; e < 3; e++) {
        int col = tid + e * 256;
        out[obase + col] = f2bf((v[e] - mean) * rs * wget(g, col, wf) + wget(b, col, wf));
    }
}

// ---------------- GEMM (unchanged from round 7) ----------------
__global__ __launch_bounds__(256) void gemm_kernel(const u16* __restrict__ A,
                                                   const void* __restrict__ W,
                                                   size_t woff, int ldw,
                                                   const void* __restrict__ bias, int boff,
                                                   void* __restrict__ Cv, size_t coff,
                                                   int M, int N, int K, int flags,
                                                   int tcmode, const int* __restrict__ blk) {
    __shared__ float As[16][64];
    __shared__ float Bs[16][64];
    int wf = blk[0];
    int tid = threadIdx.x;
    int tx = tid & 15, ty = tid >> 4;
    int row0 = blockIdx.y * 64, col0 = blockIdx.x * 64;
    float acc[4][4] = {};
    int ar = tid >> 2, ac4 = tid & 3;
    int br = tid >> 4, bc4 = tid & 15;

    for (int kb = 0; kb < K; kb += 16) {
        {
            uint2 u = *(const uint2*)(A + (size_t)(row0 + ar) * K + kb + ac4 * 4);
            float a0, a1, a2, a3;
            unpack2(u.x, a0, a1); unpack2(u.y, a2, a3);
            As[ac4 * 4 + 0][ar] = a0; As[ac4 * 4 + 1][ar] = a1;
            As[ac4 * 4 + 2][ar] = a2; As[ac4 * 4 + 3][ar] = a3;
        }
        {
            size_t off = woff + (size_t)(kb + br) * ldw + col0 + bc4 * 4;
            if (wf) {
                float4 u = *(const float4*)((const float*)W + off);
                Bs[br][bc4 * 4 + 0] = u.x; Bs[br][bc4 * 4 + 1] = u.y;
                Bs[br][bc4 * 4 + 2] = u.z; Bs[br][bc4 * 4 + 3] = u.w;
            } else {
                uint2 u = *(const uint2*)((const u16*)W + off);
                float b0, b1, b2, b3;
                unpack2(u.x, b0, b1); unpack2(u.y, b2, b3);
                Bs[br][bc4 * 4 + 0] = b0; Bs[br][bc4 * 4 + 1] = b1;
                Bs[br][bc4 * 4 + 2] = b2; Bs[br][bc4 * 4 + 3] = b3;
            }
        }
        __syncthreads();
#pragma unroll
        for (int kk = 0; kk < 16; kk++) {
            float4 a = *(const float4*)&As[kk][ty * 4];
            float4 b = *(const float4*)&Bs[kk][tx * 4];
            float av[4] = {a.x, a.y, a.z, a.w};
            float bv[4] = {b.x, b.y, b.z, b.w};
#pragma unroll
            for (int i = 0; i < 4; i++)
#pragma unroll
                for (int j = 0; j < 4; j++)
                    acc[i][j] += av[i] * bv[j];
        }
        __syncthreads();
    }

#pragma unroll
    for (int i = 0; i < 4; i++) {
        int m = row0 + ty * 4 + i;
#pragma unroll
        for (int j = 0; j < 4; j++) {
            int n = col0 + tx * 4 + j;
            float v = acc[i][j];
            if (flags & 1) v += wget(bias, boff + n, wf);
            if (flags & 2) v = 0.5f * v * (1.0f + erff(v * 0.70710678118654752f));
            size_t idx = coff + (size_t)m * N + n;
            if (tcmode == 0) {
                ((float*)Cv)[idx] += v;
            } else if (tcmode == 1) {
                ((u16*)Cv)[idx] = f2bf(v);
            } else {
                if (wf) ((float*)Cv)[idx] += v;
                else { u16* p = (u16*)Cv; p[idx] = f2bf(v + bf2f(p[idx])); }
            }
        }
    }
}

// ---------------- flash attention v2: swizzled LDS, shared K/V buffer ----------------
// 16 q-rows/block, 64-key tiles. Thread (rs=tid>>4, tx=tid&15):
//   scores: row rs, keys tx*4..+3. PV: row rs, dims d = tx + 16*i (i<6).
// Tile element (d, j) lives at kv[d][ j ^ (((d>>3)&3)<<3) ].
#define ATI 16
#define AKT 64
__global__ __launch_bounds__(256, 4) void attn_kernel(const u16* __restrict__ Q,
                                                      const u16* __restrict__ K,
                                                      const u16* __restrict__ V,
                                                      u16* __restrict__ AO,
                                                      int ldq, int ldk, int ldv, int ldo,
                                                      size_t qss, size_t kss, size_t oss,
                                                      const int* __restrict__ blk,
                                                      int bfix, int Lk, int is_self) {
    int bz   = (bfix < 0) ? blockIdx.z : 0;
    int bidx = (bfix < 0) ? blockIdx.z : bfix;
    const u16* Qp = Q + (size_t)bz * qss;
    const u16* Kp = K + (size_t)bz * kss;
    const u16* Vp = V + (size_t)bz * kss;
    u16* AOp = AO + (size_t)bz * oss;

    int hoff = blockIdx.y * HDIM;
    int i0 = blockIdx.x * ATI;
    int tid = threadIdx.x;
    int elb = blk[1 + bidx];
    int el_q = elb * blk[9];
    int el_k = is_self ? el_q : elb;

    __shared__ float qs[ATI][100];       // [r][d]
    __shared__ float kv[HDIM][68];       // swizzled tile (K, then V)
    __shared__ float ss[ATI][72];        // scores
    __shared__ float sm[ATI][16];        // partial max
    __shared__ float mrow[ATI], lrow[ATI], arow[ATI];

    int rs = tid >> 4, tx = tid & 15;
    int sj = tid / 12, sc = tid % 12;    // staging: key row sj(+t*21.33), dims sc*8..+7
    int ssw = (sc & 3) << 3;             // staging col swizzle

    if (tid < 192) {
        int r = tid / 12, c = tid % 12;
        uint4 u = *(const uint4*)(Qp + (size_t)(i0 + r) * ldq + hoff + c * 8);
        float f0, f1, f2, f3, f4, f5, f6, f7;
        unpack2(u.x, f0, f1); unpack2(u.y, f2, f3);
        unpack2(u.z, f4, f5); unpack2(u.w, f6, f7);
        float* qp = &qs[r][c * 8];
        qp[0] = f0; qp[1] = f1; qp[2] = f2; qp[3] = f3;
        qp[4] = f4; qp[5] = f5; qp[6] = f6; qp[7] = f7;
    }
    if (tid < ATI) { mrow[tid] = NEG_MASK; lrow[tid] = 0.f; }
    float o0 = 0, o1 = 0, o2 = 0, o3 = 0, o4 = 0, o5 = 0;
    __syncthreads();

    const float scale = 0.10206207261596576f;  // 1/sqrt(96)
    for (int kt0 = 0; kt0 < Lk; kt0 += AKT) {
        // ---- stage K tile (transposed + swizzled) ----
#pragma unroll
        for (int t = 0; t < 3; t++) {
            int idx = tid + t * 256;
            int j = idx / 12, c = idx % 12;
            int d0 = c * 8, col = j ^ ((c & 3) << 3);
            uint4 u = *(const uint4*)(Kp + (size_t)(kt0 + j) * ldk + hoff + c * 8);
            float f0, f1, f2, f3, f4, f5, f6, f7;
            unpack2(u.x, f0, f1); unpack2(u.y, f2, f3);
            unpack2(u.z, f4, f5); unpack2(u.w, f6, f7);
            kv[d0 + 0][col] = f0; kv[d0 + 1][col] = f1;
            kv[d0 + 2][col] = f2; kv[d0 + 3][col] = f3;
            kv[d0 + 4][col] = f4; kv[d0 + 5][col] = f5;
            kv[d0 + 6][col] = f6; kv[d0 + 7][col] = f7;
        }
        __syncthreads();

        // ---- scores ----
        float s0 = 0, s1 = 0, s2 = 0, s3 = 0;
#pragma unroll
        for (int dd = 0; dd < HDIM; dd += 8) {
            int cb = (tx * 4) ^ (((dd >> 3) & 3) << 3);
            float4 qa = *(const float4*)&qs[rs][dd];
            float4 qb = *(const float4*)&qs[rs][dd + 4];
            float4 k0 = *(const float4*)&kv[dd + 0][cb];
            s0 += qa.x * k0.x; s1 += qa.x * k0.y; s2 += qa.x * k0.z; s3 += qa.x * k0.w;
            float4 k1 = *(const float4*)&kv[dd + 1][cb];
            s0 += qa.y * k1.x; s1 += qa.y * k1.y; s2 += qa.y * k1.z; s3 += qa.y * k1.w;
            float4 k2 = *(const float4*)&kv[dd + 2][cb];
            s0 += qa.z * k2.x; s1 += qa.z * k2.y; s2 += qa.z * k2.z; s3 += qa.z * k2.w;
            float4 k3 = *(const float4*)&kv[dd + 3][cb];
            s0 += qa.w * k3.x; s1 += qa.w * k3.y; s2 += qa.w * k3.z; s3 += qa.w * k3.w;
            float4 k4 = *(const float4*)&kv[dd + 4][cb];
            s0 += qb.x * k4.x; s1 += qb.x * k4.y; s2 += qb.x * k4.z; s3 += qb.x * k4.w;
            float4 k5 = *(const float4*)&kv[dd + 5][cb];
            s0 += qb.y * k5.x; s1 += qb.y * k5.y; s2 += qb.y * k5.z; s3 += qb.y * k5.w;
            float4 k6 = *(const float4*)&kv[dd + 6][cb];
            s0 += qb.z * k6.x; s1 += qb.z * k6.y; s2 += qb.z * k6.z; s3 += qb.z * k6.w;
            float4 k7 = *(const float4*)&kv[dd + 7][cb];
            s0 += qb.w * k7.x; s1 += qb.w * k7.y; s2 += qb.w * k7.z; s3 += qb.w * k7.w;
        }
        bool vi = (i0 + rs) < el_q;
        int kb = kt0 + tx * 4;
        s0 = (vi && (kb + 0) < el_k) ? s0 * scale : NEG_MASK;
        s1 = (vi && (kb + 1) < el_k) ? s1 * scale : NEG_MASK;
        s2 = (vi && (kb + 2) < el_k) ? s2 * scale : NEG_MASK;
        s3 = (vi && (kb + 3) < el_k) ? s3 * scale : NEG_MASK;
        *(float4*)&ss[rs][tx * 4] = make_float4(s0, s1, s2, s3);
        sm[rs][tx] = fmaxf(fmaxf(s0, s1), fmaxf(s2, s3));
        __syncthreads();

        // ---- running max (threads 0..15) + stage V over kv ----
        if (tid < ATI) {
            int r = tid;
            float mo = mrow[r];
            float mt = mo;
#pragma unroll
            for (int t = 0; t < 16; t += 4) {
                float4 a = *(const float4*)&sm[r][t];
                mt = fmaxf(mt, fmaxf(fmaxf(a.x, a.y), fmaxf(a.z, a.w)));
            }
            float alpha = __expf(mo - mt);
            mrow[r] = mt; arow[r] = alpha;
            lrow[r] *= alpha;
        }
#pragma unroll
        for (int t = 0; t < 3; t++) {
            int idx = tid + t * 256;
            int j = idx / 12, c = idx % 12;
            int d0 = c * 8, col = j ^ ((c & 3) << 3);
            uint4 u = *(const uint4*)(Vp + (size_t)(kt0 + j) * ldv + hoff + c * 8);
            float f0, f1, f2, f3, f4, f5, f6, f7;
            unpack2(u.x, f0, f1); unpack2(u.y, f2, f3);
            unpack2(u.z, f4, f5); unpack2(u.w, f6, f7);
            kv[d0 + 0][col] = f0; kv[d0 + 1][col] = f1;
            kv[d0 + 2][col] = f2; kv[d0 + 3][col] = f3;
            kv[d0 + 4][col] = f4; kv[d0 + 5][col] = f5;
            kv[d0 + 6][col] = f6; kv[d0 + 7][col] = f7;
        }
        __syncthreads();

        // ---- PV with fused exp ----
        float mt = mrow[rs];
        float al = arow[rs];
        o0 *= al; o1 *= al; o2 *= al; o3 *= al; o4 *= al; o5 *= al;
        float lsum = 0.f;
#pragma unroll
        for (int k = 0; k < AKT; k += 4) {
            float4 sv = *(const float4*)&ss[rs][k];
            float p0 = __expf(sv.x - mt);
            float p1 = __expf(sv.y - mt);
            float p2 = __expf(sv.z - mt);
            float p3 = __expf(sv.w - mt);
            lsum += p0 + p1 + p2 + p3;
#pragma unroll
            for (int i = 0; i < 6; i++) {
                int d = tx + 16 * i;
                int cb = k ^ (((d >> 3) & 3) << 3);
                float4 v = *(const float4*)&kv[d][cb];
                float acc = p0 * v.x + p1 * v.y + p2 * v.z + p3 * v.w;
                if (i == 0) o0 += acc;
                else if (i == 1) o1 += acc;
                else if (i == 2) o2 += acc;
                else if (i == 3) o3 += acc;
                else if (i == 4) o4 += acc;
                else o5 += acc;
            }
        }
        if (tx == 0) lrow[rs] += lsum;
        __syncthreads();
    }

    float inv = 1.0f / lrow[rs];
    size_t ob = (size_t)(i0 + rs) * ldo + hoff + tx;
    AOp[ob + 0]  = f2bf(o0 * inv);
    AOp[ob + 16] = f2bf(o1 * inv);
    AOp[ob + 32] = f2bf(o2 * inv);
    AOp[ob + 48] = f2bf(o3 * inv);
    AOp[ob + 64] = f2bf(o4 * inv);
    AOp[ob + 80] = f2bf(o5 * inv);
}

// ---------------- launcher ----------------
extern "C" void kernel_launch(void* const* d_in, const int* in_sizes, int n_in,
                              void* d_out, int out_size, void* d_ws, size_t ws_size,
                              hipStream_t stream) {
    const void* x    = d_in[0];
    const void* c    = d_in[1];
    const int* el    = (const int*)d_in[2];
    const int* us    = (const int*)d_in[3];
    const void* Wq1  = d_in[4];
    const void* Wkv1 = d_in[5];
    const void* Wo1  = d_in[6];
    const void* bo1  = d_in[7];
    const void* Wq2  = d_in[8];
    const void* Wkv2 = d_in[9];
    const void* Wo2  = d_in[10];
    const void* bo2  = d_in[11];
    const void* g1 = d_in[12]; const void* b1 = d_in[13];
    const void* g2 = d_in[14]; const void* b2 = d_in[15];
    const void* g4 = d_in[16]; const void* b4 = d_in[17];
    const void* gc = d_in[18]; const void* bc = d_in[19];
    const void* Wf1 = d_in[20]; const void* bf1 = d_in[21];
    const void* Wf2 = d_in[22]; const void* bf2 = d_in[23];

    const int B = 8, S = 512, L = 1024, C = EMBED;
    const int NX = B * L * C;
    const size_t RL = (size_t)L * C;
    const size_t RS = (size_t)S * C;

    char* ws = (char*)d_ws;
    int*  blk = (int*)ws;
    dim3 blkd(256);

    bool tierA = ws_size >= (size_t)88080448;
    bool tierB = !tierA && ws_size >= (size_t)33030208;

    detect_kernel<<<1, 64, 0, stream>>>((const u16*)x, el, us, blk);

    if (tierA) {
        float* X  = (float*)(ws + 64);
        u16*   XN = (u16*)(ws + 64 + 25165824);
        char*  P  = ws + 64 + 25165824 + 12582912;
        u16* Qb   = (u16*)P;
        u16* KVb  = (u16*)(P + 12582912);
        u16* AOb  = (u16*)(P + 37748736);
        u16* CNb  = (u16*)P;
        u16* KV2b = (u16*)(P + 6291456);
        u16* Q2b  = (u16*)(P + 18874368);
        u16* AO2b = (u16*)(P + 31457280);
        u16* Hb   = (u16*)P;

        wire_to_f32<<<(NX + 255) / 256, blkd, 0, stream>>>(x, 0, X, NX, blk);

        ln_kernel<<<B * L, blkd, 0, stream>>>(X, 0, 0, g1, b1, XN, blk);
        gemm_kernel<<<dim3(12, 128), blkd, 0, stream>>>(XN, Wq1, 0, C, nullptr, 0, Qb, 0, B * L, C, C, 0, 1, blk);
        gemm_kernel<<<dim3(24, 128), blkd, 0, stream>>>(XN, Wkv1, 0, 2 * C, nullptr, 0, KVb, 0, B * L, 2 * C, C, 0, 1, blk);
        attn_kernel<<<dim3(64, 8, 8), blkd, 0, stream>>>(Qb, KVb, KVb + C, AOb, C, 2 * C, 2 * C, C,
                                                         RL, (size_t)L * 2 * C, RL, blk, -1, L, 1);
        gemm_kernel<<<dim3(12, 128), blkd, 0, stream>>>(AOb, Wo1, 0, C, bo1, 0, X, 0, B * L, C, C, 1, 0, blk);

        ln_kernel<<<B * L, blkd, 0, stream>>>(X, 0, 0, g2, b2, XN, blk);
        ln_kernel<<<B * S, blkd, 0, stream>>>(c, 0, 2, gc, bc, CNb, blk);
        gemm_kernel<<<dim3(24, 64), blkd, 0, stream>>>(CNb, Wkv2, 0, 2 * C, nullptr, 0, KV2b, 0, B * S, 2 * C, C, 0, 1, blk);
        gemm_kernel<<<dim3(12, 128), blkd, 0, stream>>>(XN, Wq2, 0, C, nullptr, 0, Q2b, 0, B * L, C, C, 0, 1, blk);
        attn_kernel<<<dim3(64, 8, 8), blkd, 0, stream>>>(Q2b, KV2b, KV2b + C, AO2b, C, 2 * C, 2 * C, C,
                                                         RL, (size_t)S * 2 * C, RL, blk, -1, S, 0);
        gemm_kernel<<<dim3(12, 128), blkd, 0, stream>>>(AO2b, Wo2, 0, C, bo2, 0, X, 0, B * L, C, C, 1, 0, blk);

        ln_kernel<<<B * L, blkd, 0, stream>>>(X, 0, 0, g4, b4, XN, blk);
        gemm_kernel<<<dim3(48, 128), blkd, 0, stream>>>(XN, Wf1, 0, 4 * C, bf1, 0, Hb, 0, B * L, 4 * C, C, 1 | 2, 1, blk);
        gemm_kernel<<<dim3(12, 128), blkd, 0, stream>>>(Hb, Wf2, 0, C, bf2, 0, X, 0, B * L, C, 4 * C, 1, 0, blk);

        f32_to_out<<<(NX + 255) / 256, blkd, 0, stream>>>(X, d_out, 0, NX, blk);
    } else if (tierB) {
        float* X  = (float*)(ws + 64);
        u16*   XN = (u16*)(ws + 64 + 25165824);
        char*  P  = ws + 64 + 25165824 + 1572864;
        u16* Qb   = (u16*)P;
        u16* KVb  = (u16*)(P + 1572864);
        u16* AOb  = (u16*)(P + 4718592);
        u16* CNb  = (u16*)P;
        u16* KV2b = (u16*)(P + 786432);
        u16* Q2b  = (u16*)(P + 2359296);
        u16* AO2b = (u16*)(P + 3932160);
        u16* Hb   = (u16*)P;

        wire_to_f32<<<(NX + 255) / 256, blkd, 0, stream>>>(x, 0, X, NX, blk);

        for (int b = 0; b < B; b++) {
            size_t ro = (size_t)b * RL;
            ln_kernel<<<L, blkd, 0, stream>>>(X, ro, 0, g1, b1, XN, blk);
            gemm_kernel<<<dim3(12, 16), blkd, 0, stream>>>(XN, Wq1, 0, C, nullptr, 0, Qb, 0, L, C, C, 0, 1, blk);
            gemm_kernel<<<dim3(24, 16), blkd, 0, stream>>>(XN, Wkv1, 0, 2 * C, nullptr, 0, KVb, 0, L, 2 * C, C, 0, 1, blk);
            attn_kernel<<<dim3(64, 8), blkd, 0, stream>>>(Qb, KVb, KVb + C, AOb, C, 2 * C, 2 * C, C, 0, 0, 0, blk, b, L, 1);
            gemm_kernel<<<dim3(12, 16), blkd, 0, stream>>>(AOb, Wo1, 0, C, bo1, 0, X, ro, L, C, C, 1, 0, blk);

            ln_kernel<<<L, blkd, 0, stream>>>(X, ro, 0, g2, b2, XN, blk);
            ln_kernel<<<S, blkd, 0, stream>>>(c, (size_t)b * RS, 2, gc, bc, CNb, blk);
            gemm_kernel<<<dim3(24, 8), blkd, 0, stream>>>(CNb, Wkv2, 0, 2 * C, nullptr, 0, KV2b, 0, S, 2 * C, C, 0, 1, blk);
            gemm_kernel<<<dim3(12, 16), blkd, 0, stream>>>(XN, Wq2, 0, C, nullptr, 0, Q2b, 0, L, C, C, 0, 1, blk);
            attn_kernel<<<dim3(64, 8), blkd, 0, stream>>>(Q2b, KV2b, KV2b + C, AO2b, C, 2 * C, 2 * C, C, 0, 0, 0, blk, b, S, 0);
            gemm_kernel<<<dim3(12, 16), blkd, 0, stream>>>(AO2b, Wo2, 0, C, bo2, 0, X, ro, L, C, C, 1, 0, blk);

            ln_kernel<<<L, blkd, 0, stream>>>(X, ro, 0, g4, b4, XN, blk);
            gemm_kernel<<<dim3(48, 16), blkd, 0, stream>>>(XN, Wf1, 0, 4 * C, bf1, 0, Hb, 0, L, 4 * C, C, 1 | 2, 1, blk);
            gemm_kernel<<<dim3(12, 16), blkd, 0, stream>>>(Hb, Wf2, 0, C, bf2, 0, X, ro, L, C, 4 * C, 1, 0, blk);
        }
        f32_to_out<<<(NX + 255) / 256, blkd, 0, stream>>>(X, d_out, 0, NX, blk);
    } else {
        u16*  XN  = (u16*)(ws + 64);
        u16*  CNb = (u16*)(ws + 64 + 1572864);
        char* P2  = ws + 64 + 1572864 + 786432;
        u16* Qp  = (u16*)P2;
        u16* Kp  = (u16*)(P2 + 393216);
        u16* Vp  = (u16*)(P2 + 786432);
        u16* AOp = (u16*)(P2 + 1179648);
        u16* Hc  = (u16*)P2;

        wire_copy<<<(NX + 255) / 256, blkd, 0, stream>>>(x, d_out, NX, blk);

        for (int b = 0; b < B; b++) {
            size_t ro = (size_t)b * RL;

            ln_kernel<<<L, blkd, 0, stream>>>(d_out, ro, 2, g1, b1, XN, blk);
            for (int p = 0; p < 4; p++) {
                int h = 2 * p;
                gemm_kernel<<<dim3(3, 16), blkd, 0, stream>>>(XN, Wq1, (size_t)h * 96, C, nullptr, 0, Qp, 0, L, 192, C, 0, 1, blk);
                gemm_kernel<<<dim3(3, 16), blkd, 0, stream>>>(XN, Wkv1, (size_t)h * 96, 2 * C, nullptr, 0, Kp, 0, L, 192, C, 0, 1, blk);
                gemm_kernel<<<dim3(3, 16), blkd, 0, stream>>>(XN, Wkv1, (size_t)(C + h * 96), 2 * C, nullptr, 0, Vp, 0, L, 192, C, 0, 1, blk);
                attn_kernel<<<dim3(64, 2), blkd, 0, stream>>>(Qp, Kp, Vp, AOp, 192, 192, 192, 192, 0, 0, 0, blk, b, L, 1);
                gemm_kernel<<<dim3(12, 16), blkd, 0, stream>>>(AOp, Wo1, (size_t)h * 96 * C, C, bo1, 0, d_out, ro, L, C, 192, (p == 0) ? 1 : 0, 3, blk);
            }
            ln_kernel<<<L, blkd, 0, stream>>>(d_out, ro, 2, g2, b2, XN, blk);
            ln_kernel<<<S, blkd, 0, stream>>>(c, (size_t)b * RS, 2, gc, bc, CNb, blk);
            for (int p = 0; p < 4; p++) {
                int h = 2 * p;
                gemm_kernel<<<dim3(3, 16), blkd, 0, stream>>>(XN, Wq2, (size_t)h * 96, C, nullptr, 0, Qp, 0, L, 192, C, 0, 1, blk);
                gemm_kernel<<<dim3(3, 8), blkd, 0, stream>>>(CNb, Wkv2, (size_t)h * 96, 2 * C, nullptr, 0, Kp, 0, S, 192, C, 0, 1, blk);
                gemm_kernel<<<dim3(3, 8), blkd, 0, stream>>>(CNb, Wkv2, (size_t)(C + h * 96), 2 * C, nullptr, 0, Vp, 0, S, 192, C, 0, 1, blk);
                attn_kernel<<<dim3(64, 2), blkd, 0, stream>>>(Qp, Kp, Vp, AOp, 192, 192, 192, 192, 0, 0, 0, blk, b, S, 0);
                gemm_kernel<<<dim3(12, 16), blkd, 0, stream>>>(AOp, Wo2, (size_t)h * 96 * C, C, bo2, 0, d_out, ro, L, C, 192, (p == 0) ? 1 : 0, 3, blk);
            }
            ln_kernel<<<L, blkd, 0, stream>>>(d_out, ro, 2, g4, b4, XN, blk);
            for (int ch = 0; ch < 4; ch++) {
                gemm_kernel<<<dim3(12, 16), blkd, 0, stream>>>(XN, Wf1, (size_t)ch * C, 4 * C, bf1, ch * C, Hc, 0, L, C, C, 1 | 2, 1, blk);
                gemm_kernel<<<dim3(12, 16), blkd, 0, stream>>>(Hc, Wf2, (size_t)ch * C * C, C, bf2, 0, d_out, ro, L, C, C, (ch == 0) ? 1 : 0, 3, blk);
            }
        }
    }
}

// Round 9
// 3318.083 us; speedup vs baseline: 6.6937x; 6.6937x over previous
//
#include <hip/hip_runtime.h>
#include <math.h>

#define EMBED 768
#define HEADS 8
#define HDIM  96
#define NEG_MASK (-1.0e30f)

typedef unsigned short u16;
typedef unsigned int   u32;

__device__ __forceinline__ float bf2f(u16 u) {
    return __uint_as_float(((u32)u) << 16);
}
__device__ __forceinline__ u16 f2bf(float f) {
    u32 x = __float_as_uint(f);
    u32 r = (x + 0x7fffu + ((x >> 16) & 1u)) >> 16;
    return (u16)r;
}
__device__ __forceinline__ void unpack2(u32 w, float& lo, float& hi) {
    lo = __uint_as_float(w << 16);
    hi = __uint_as_float(w & 0xffff0000u);
}
__device__ __forceinline__ float wget(const void* p, size_t i, int wf) {
    return wf ? ((const float*)p)[i] : bf2f(((const u16*)p)[i]);
}

// ---------------- detection ----------------
__global__ __launch_bounds__(64) void detect_kernel(const u16* __restrict__ x,
                                                    const int* __restrict__ el,
                                                    const int* __restrict__ usp,
                                                    int* __restrict__ blk) {
    int lane = threadIdx.x;
    int cnt = 0;
    for (int i = lane; i < 4096; i += 64) {
        u32 e = (x[i] >> 7) & 0xFFu;
        if (e >= 0xC0u) cnt++;
    }
#pragma unroll
    for (int off = 32; off > 0; off >>= 1) cnt += __shfl_xor(cnt, off, 64);
    if (lane == 0) {
        blk[0] = (cnt > 32) ? 1 : 0;
        bool i64 = (el[1] == 0) && (el[3] == 0) && (el[5] == 0) && (el[7] == 0);
        for (int b = 0; b < 8; b++) blk[1 + b] = i64 ? el[2 * b] : el[b];
        blk[9] = usp[0];
    }
}

// ---------------- copies ----------------
__global__ void wire_to_f32(const void* __restrict__ in, size_t ioff,
                            float* __restrict__ out, int n,
                            const int* __restrict__ blk) {
    int i = blockIdx.x * blockDim.x + threadIdx.x;
    int wf = blk[0];
    if (i < n) out[i] = wget(in, ioff + (size_t)i, wf);
}
__global__ void wire_copy(const void* __restrict__ in, void* __restrict__ out,
                          int n, const int* __restrict__ blk) {
    int i = blockIdx.x * blockDim.x + threadIdx.x;
    int wf = blk[0];
    if (i < n) {
        if (wf) ((float*)out)[i] = ((const float*)in)[i];
        else    ((u16*)out)[i]   = ((const u16*)in)[i];
    }
}
__global__ void f32_to_out(const float* __restrict__ in, void* __restrict__ out,
                           size_t ooff, int n, const int* __restrict__ blk) {
    int i = blockIdx.x * blockDim.x + threadIdx.x;
    int wf = blk[0];
    if (i < n) {
        if (wf) ((float*)out)[ooff + i] = in[i];
        else    ((u16*)out)[ooff + i]   = f2bf(in[i]);
    }
}

// ---------------- LayerNorm ----------------
__global__ __launch_bounds__(256) void ln_kernel(const void* __restrict__ in,
                                                 size_t ioff, int sel,
                                                 const void* __restrict__ g,
                                                 const void* __restrict__ b,
                                                 u16* __restrict__ out,
                                                 const int* __restrict__ blk) {
    int wf = blk[0];
    int row = blockIdx.x, tid = threadIdx.x;
    size_t base = ioff + (size_t)row * EMBED;
    float v[3];
#pragma unroll
    for (int e = 0; e < 3; e++) {
        size_t idx = base + tid + e * 256;
        v[e] = (sel == 0) ? ((const float*)in)[idx] : wget(in, idx, wf);
    }
    float s = v[0] + v[1] + v[2];
    float q = v[0] * v[0] + v[1] * v[1] + v[2] * v[2];
#pragma unroll
    for (int off = 32; off > 0; off >>= 1) {
        s += __shfl_xor(s, off, 64);
        q += __shfl_xor(q, off, 64);
    }
    __shared__ float sb[8];
    int wid = tid >> 6, lane = tid & 63;
    if (lane == 0) { sb[wid] = s; sb[4 + wid] = q; }
    __syncthreads();
    if (tid == 0) {
        sb[0] = sb[0] + sb[1] + sb[2] + sb[3];
        sb[4] = sb[4] + sb[5] + sb[6] + sb[7];
    }
    __syncthreads();
    float mean = sb[0] * (1.0f / EMBED);
    float var  = sb[4] * (1.0f / EMBED) - mean * mean;
    float rs   = rsqrtf(var + 1e-5f);
    size_t obase = (size_t)row * EMBED;
#pragma unroll
    for (int e = 0; e < 3; e++) {
        int col = tid + e * 256;
        out[obase + col] = f2bf((v[e] - mean) * rs * wget(g, col, wf) + wget(b, col, wf));
    }
}

// ---------------- GEMM (unchanged) ----------------
__global__ __launch_bounds__(256) void gemm_kernel(const u16* __restrict__ A,
                                                   const void* __restrict__ W,
                                                   size_t woff, int ldw,
                                                   const void* __restrict__ bias, int boff,
                                                   void* __restrict__ Cv, size_t coff,
                                                   int M, int N, int K, int flags,
                                                   int tcmode, const int* __restrict__ blk) {
    __shared__ float As[16][64];
    __shared__ float Bs[16][64];
    int wf = blk[0];
    int tid = threadIdx.x;
    int tx = tid & 15, ty = tid >> 4;
    int row0 = blockIdx.y * 64, col0 = blockIdx.x * 64;
    float acc[4][4] = {};
    int ar = tid >> 2, ac4 = tid & 3;
    int br = tid >> 4, bc4 = tid & 15;

    for (int kb = 0; kb < K; kb += 16) {
        {
            uint2 u = *(const uint2*)(A + (size_t)(row0 + ar) * K + kb + ac4 * 4);
            float a0, a1, a2, a3;
            unpack2(u.x, a0, a1); unpack2(u.y, a2, a3);
            As[ac4 * 4 + 0][ar] = a0; As[ac4 * 4 + 1][ar] = a1;
            As[ac4 * 4 + 2][ar] = a2; As[ac4 * 4 + 3][ar] = a3;
        }
        {
            size_t off = woff + (size_t)(kb + br) * ldw + col0 + bc4 * 4;
            if (wf) {
                float4 u = *(const float4*)((const float*)W + off);
                Bs[br][bc4 * 4 + 0] = u.x; Bs[br][bc4 * 4 + 1] = u.y;
                Bs[br][bc4 * 4 + 2] = u.z; Bs[br][bc4 * 4 + 3] = u.w;
            } else {
                uint2 u = *(const uint2*)((const u16*)W + off);
                float b0, b1, b2, b3;
                unpack2(u.x, b0, b1); unpack2(u.y, b2, b3);
                Bs[br][bc4 * 4 + 0] = b0; Bs[br][bc4 * 4 + 1] = b1;
                Bs[br][bc4 * 4 + 2] = b2; Bs[br][bc4 * 4 + 3] = b3;
            }
        }
        __syncthreads();
#pragma unroll
        for (int kk = 0; kk < 16; kk++) {
            float4 a = *(const float4*)&As[kk][ty * 4];
            float4 b = *(const float4*)&Bs[kk][tx * 4];
            float av[4] = {a.x, a.y, a.z, a.w};
            float bv[4] = {b.x, b.y, b.z, b.w};
#pragma unroll
            for (int i = 0; i < 4; i++)
#pragma unroll
                for (int j = 0; j < 4; j++)
                    acc[i][j] += av[i] * bv[j];
        }
        __syncthreads();
    }

#pragma unroll
    for (int i = 0; i < 4; i++) {
        int m = row0 + ty * 4 + i;
#pragma unroll
        for (int j = 0; j < 4; j++) {
            int n = col0 + tx * 4 + j;
            float v = acc[i][j];
            if (flags & 1) v += wget(bias, boff + n, wf);
            if (flags & 2) v = 0.5f * v * (1.0f + erff(v * 0.70710678118654752f));
            size_t idx = coff + (size_t)m * N + n;
            if (tcmode == 0) {
                ((float*)Cv)[idx] += v;
            } else if (tcmode == 1) {
                ((u16*)Cv)[idx] = f2bf(v);
            } else {
                if (wf) ((float*)Cv)[idx] += v;
                else { u16* p = (u16*)Cv; p[idx] = f2bf(v + bf2f(p[idx])); }
            }
        }
    }
}

// ---------------- flash attention v3: swizzled LDS, shared K/V buffer,
// NO register-forcing launch bounds (round 8's (256,4) caused catastrophic
// scratch spills: VGPR 64, FETCH 19.8 GB/dispatch). Register pressure is
// instead bounded structurally: outer loops are #pragma unroll 1 so only a
// small inner body's values are live at once.
#define ATI 16
#define AKT 64
__global__ __launch_bounds__(256) void attn_kernel(const u16* __restrict__ Q,
                                                   const u16* __restrict__ K,
                                                   const u16* __restrict__ V,
                                                   u16* __restrict__ AO,
                                                   int ldq, int ldk, int ldv, int ldo,
                                                   size_t qss, size_t kss, size_t oss,
                                                   const int* __restrict__ blk,
                                                   int bfix, int Lk, int is_self) {
    int bz   = (bfix < 0) ? blockIdx.z : 0;
    int bidx = (bfix < 0) ? blockIdx.z : bfix;
    const u16* Qp = Q + (size_t)bz * qss;
    const u16* Kp = K + (size_t)bz * kss;
    const u16* Vp = V + (size_t)bz * kss;
    u16* AOp = AO + (size_t)bz * oss;

    int hoff = blockIdx.y * HDIM;
    int i0 = blockIdx.x * ATI;
    int tid = threadIdx.x;
    int elb = blk[1 + bidx];
    int el_q = elb * blk[9];
    int el_k = is_self ? el_q : elb;

    __shared__ float qs[ATI][100];       // [r][d]
    __shared__ float kv[HDIM][68];       // swizzled tile (K, then V)
    __shared__ float ss[ATI][72];        // scores
    __shared__ float sm[ATI][16];        // partial max
    __shared__ float mrow[ATI], lrow[ATI], arow[ATI];

    int rs = tid >> 4, tx = tid & 15;

    if (tid < 192) {
        int r = tid / 12, c = tid % 12;
        uint4 u = *(const uint4*)(Qp + (size_t)(i0 + r) * ldq + hoff + c * 8);
        float f0, f1, f2, f3, f4, f5, f6, f7;
        unpack2(u.x, f0, f1); unpack2(u.y, f2, f3);
        unpack2(u.z, f4, f5); unpack2(u.w, f6, f7);
        float* qp = &qs[r][c * 8];
        qp[0] = f0; qp[1] = f1; qp[2] = f2; qp[3] = f3;
        qp[4] = f4; qp[5] = f5; qp[6] = f6; qp[7] = f7;
    }
    if (tid < ATI) { mrow[tid] = NEG_MASK; lrow[tid] = 0.f; }
    float o0 = 0, o1 = 0, o2 = 0, o3 = 0, o4 = 0, o5 = 0;
    __syncthreads();

    const float scale = 0.10206207261596576f;  // 1/sqrt(96)
    for (int kt0 = 0; kt0 < Lk; kt0 += AKT) {
        // ---- stage K tile (transposed + swizzled) ----
#pragma unroll 1
        for (int t = 0; t < 3; t++) {
            int idx = tid + t * 256;
            int j = idx / 12, c = idx % 12;
            int d0 = c * 8, col = j ^ ((c & 3) << 3);
            uint4 u = *(const uint4*)(Kp + (size_t)(kt0 + j) * ldk + hoff + c * 8);
            float f0, f1, f2, f3, f4, f5, f6, f7;
            unpack2(u.x, f0, f1); unpack2(u.y, f2, f3);
            unpack2(u.z, f4, f5); unpack2(u.w, f6, f7);
            kv[d0 + 0][col] = f0; kv[d0 + 1][col] = f1;
            kv[d0 + 2][col] = f2; kv[d0 + 3][col] = f3;
            kv[d0 + 4][col] = f4; kv[d0 + 5][col] = f5;
            kv[d0 + 6][col] = f6; kv[d0 + 7][col] = f7;
        }
        __syncthreads();

        // ---- scores: outer blocks of 24 dims (pressure-bounded) ----
        float s0 = 0, s1 = 0, s2 = 0, s3 = 0;
#pragma unroll 1
        for (int db = 0; db < HDIM; db += 24) {
#pragma unroll
            for (int dd = db; dd < db + 24; dd += 4) {
                int cb = (tx * 4) ^ (((dd >> 3) & 3) << 3);
                float4 q = *(const float4*)&qs[rs][dd];
                float4 k0 = *(const float4*)&kv[dd + 0][cb];
                s0 += q.x * k0.x; s1 += q.x * k0.y; s2 += q.x * k0.z; s3 += q.x * k0.w;
                float4 k1 = *(const float4*)&kv[dd + 1][cb];
                s0 += q.y * k1.x; s1 += q.y * k1.y; s2 += q.y * k1.z; s3 += q.y * k1.w;
                float4 k2 = *(const float4*)&kv[dd + 2][cb];
                s0 += q.z * k2.x; s1 += q.z * k2.y; s2 += q.z * k2.z; s3 += q.z * k2.w;
                float4 k3 = *(const float4*)&kv[dd + 3][cb];
                s0 += q.w * k3.x; s1 += q.w * k3.y; s2 += q.w * k3.z; s3 += q.w * k3.w;
            }
        }
        bool vi = (i0 + rs) < el_q;
        int kb = kt0 + tx * 4;
        s0 = (vi && (kb + 0) < el_k) ? s0 * scale : NEG_MASK;
        s1 = (vi && (kb + 1) < el_k) ? s1 * scale : NEG_MASK;
        s2 = (vi && (kb + 2) < el_k) ? s2 * scale : NEG_MASK;
        s3 = (vi && (kb + 3) < el_k) ? s3 * scale : NEG_MASK;
        *(float4*)&ss[rs][tx * 4] = make_float4(s0, s1, s2, s3);
        sm[rs][tx] = fmaxf(fmaxf(s0, s1), fmaxf(s2, s3));
        __syncthreads();

        // ---- running max (threads 0..15) + stage V over kv ----
        if (tid < ATI) {
            int r = tid;
            float mo = mrow[r];
            float mt = mo;
#pragma unroll
            for (int t = 0; t < 16; t += 4) {
                float4 a = *(const float4*)&sm[r][t];
                mt = fmaxf(mt, fmaxf(fmaxf(a.x, a.y), fmaxf(a.z, a.w)));
            }
            float alpha = __expf(mo - mt);
            mrow[r] = mt; arow[r] = alpha;
            lrow[r] *= alpha;
        }
#pragma unroll 1
        for (int t = 0; t < 3; t++) {
            int idx = tid + t * 256;
            int j = idx / 12, c = idx % 12;
            int d0 = c * 8, col = j ^ ((c & 3) << 3);
            uint4 u = *(const uint4*)(Vp + (size_t)(kt0 + j) * ldv + hoff + c * 8);
            float f0, f1, f2, f3, f4, f5, f6, f7;
            unpack2(u.x, f0, f1); unpack2(u.y, f2, f3);
            unpack2(u.z, f4, f5); unpack2(u.w, f6, f7);
            kv[d0 + 0][col] = f0; kv[d0 + 1][col] = f1;
            kv[d0 + 2][col] = f2; kv[d0 + 3][col] = f3;
            kv[d0 + 4][col] = f4; kv[d0 + 5][col] = f5;
            kv[d0 + 6][col] = f6; kv[d0 + 7][col] = f7;
        }
        __syncthreads();

        // ---- PV with fused exp: outer blocks of 16 keys ----
        float mt = mrow[rs];
        float al = arow[rs];
        o0 *= al; o1 *= al; o2 *= al; o3 *= al; o4 *= al; o5 *= al;
        float lsum = 0.f;
#pragma unroll 1
        for (int kb2 = 0; kb2 < AKT; kb2 += 16) {
#pragma unroll
            for (int k = kb2; k < kb2 + 16; k += 4) {
                float4 sv = *(const float4*)&ss[rs][k];
                float p0 = __expf(sv.x - mt);
                float p1 = __expf(sv.y - mt);
                float p2 = __expf(sv.z - mt);
                float p3 = __expf(sv.w - mt);
                lsum += p0 + p1 + p2 + p3;
#pragma unroll
                for (int i = 0; i < 6; i++) {
                    int d = tx + 16 * i;
                    int cb = k ^ (((d >> 3) & 3) << 3);
                    float4 v = *(const float4*)&kv[d][cb];
                    float acc = p0 * v.x + p1 * v.y + p2 * v.z + p3 * v.w;
                    if (i == 0) o0 += acc;
                    else if (i == 1) o1 += acc;
                    else if (i == 2) o2 += acc;
                    else if (i == 3) o3 += acc;
                    else if (i == 4) o4 += acc;
                    else o5 += acc;
                }
            }
        }
        if (tx == 0) lrow[rs] += lsum;
        __syncthreads();
    }

    float inv = 1.0f / lrow[rs];
    size_t ob = (size_t)(i0 + rs) * ldo + hoff + tx;
    AOp[ob + 0]  = f2bf(o0 * inv);
    AOp[ob + 16] = f2bf(o1 * inv);
    AOp[ob + 32] = f2bf(o2 * inv);
    AOp[ob + 48] = f2bf(o3 * inv);
    AOp[ob + 64] = f2bf(o4 * inv);
    AOp[ob + 80] = f2bf(o5 * inv);
}

// ---------------- launcher ----------------
extern "C" void kernel_launch(void* const* d_in, const int* in_sizes, int n_in,
                              void* d_out, int out_size, void* d_ws, size_t ws_size,
                              hipStream_t stream) {
    const void* x    = d_in[0];
    const void* c    = d_in[1];
    const int* el    = (const int*)d_in[2];
    const int* us    = (const int*)d_in[3];
    const void* Wq1  = d_in[4];
    const void* Wkv1 = d_in[5];
    const void* Wo1  = d_in[6];
    const void* bo1  = d_in[7];
    const void* Wq2  = d_in[8];
    const void* Wkv2 = d_in[9];
    const void* Wo2  = d_in[10];
    const void* bo2  = d_in[11];
    const void* g1 = d_in[12]; const void* b1 = d_in[13];
    const void* g2 = d_in[14]; const void* b2 = d_in[15];
    const void* g4 = d_in[16]; const void* b4 = d_in[17];
    const void* gc = d_in[18]; const void* bc = d_in[19];
    const void* Wf1 = d_in[20]; const void* bf1 = d_in[21];
    const void* Wf2 = d_in[22]; const void* bf2 = d_in[23];

    const int B = 8, S = 512, L = 1024, C = EMBED;
    const int NX = B * L * C;
    const size_t RL = (size_t)L * C;
    const size_t RS = (size_t)S * C;

    char* ws = (char*)d_ws;
    int*  blk = (int*)ws;
    dim3 blkd(256);

    bool tierA = ws_size >= (size_t)88080448;
    bool tierB = !tierA && ws_size >= (size_t)33030208;

    detect_kernel<<<1, 64, 0, stream>>>((const u16*)x, el, us, blk);

    if (tierA) {
        float* X  = (float*)(ws + 64);
        u16*   XN = (u16*)(ws + 64 + 25165824);
        char*  P  = ws + 64 + 25165824 + 12582912;
        u16* Qb   = (u16*)P;
        u16* KVb  = (u16*)(P + 12582912);
        u16* AOb  = (u16*)(P + 37748736);
        u16* CNb  = (u16*)P;
        u16* KV2b = (u16*)(P + 6291456);
        u16* Q2b  = (u16*)(P + 18874368);
        u16* AO2b = (u16*)(P + 31457280);
        u16* Hb   = (u16*)P;

        wire_to_f32<<<(NX + 255) / 256, blkd, 0, stream>>>(x, 0, X, NX, blk);

        ln_kernel<<<B * L, blkd, 0, stream>>>(X, 0, 0, g1, b1, XN, blk);
        gemm_kernel<<<dim3(12, 128), blkd, 0, stream>>>(XN, Wq1, 0, C, nullptr, 0, Qb, 0, B * L, C, C, 0, 1, blk);
        gemm_kernel<<<dim3(24, 128), blkd, 0, stream>>>(XN, Wkv1, 0, 2 * C, nullptr, 0, KVb, 0, B * L, 2 * C, C, 0, 1, blk);
        attn_kernel<<<dim3(64, 8, 8), blkd, 0, stream>>>(Qb, KVb, KVb + C, AOb, C, 2 * C, 2 * C, C,
                                                         RL, (size_t)L * 2 * C, RL, blk, -1, L, 1);
        gemm_kernel<<<dim3(12, 128), blkd, 0, stream>>>(AOb, Wo1, 0, C, bo1, 0, X, 0, B * L, C, C, 1, 0, blk);

        ln_kernel<<<B * L, blkd, 0, stream>>>(X, 0, 0, g2, b2, XN, blk);
        ln_kernel<<<B * S, blkd, 0, stream>>>(c, 0, 2, gc, bc, CNb, blk);
        gemm_kernel<<<dim3(24, 64), blkd, 0, stream>>>(CNb, Wkv2, 0, 2 * C, nullptr, 0, KV2b, 0, B * S, 2 * C, C, 0, 1, blk);
        gemm_kernel<<<dim3(12, 128), blkd, 0, stream>>>(XN, Wq2, 0, C, nullptr, 0, Q2b, 0, B * L, C, C, 0, 1, blk);
        attn_kernel<<<dim3(64, 8, 8), blkd, 0, stream>>>(Q2b, KV2b, KV2b + C, AO2b, C, 2 * C, 2 * C, C,
                                                         RL, (size_t)S * 2 * C, RL, blk, -1, S, 0);
        gemm_kernel<<<dim3(12, 128), blkd, 0, stream>>>(AO2b, Wo2, 0, C, bo2, 0, X, 0, B * L, C, C, 1, 0, blk);

        ln_kernel<<<B * L, blkd, 0, stream>>>(X, 0, 0, g4, b4, XN, blk);
        gemm_kernel<<<dim3(48, 128), blkd, 0, stream>>>(XN, Wf1, 0, 4 * C, bf1, 0, Hb, 0, B * L, 4 * C, C, 1 | 2, 1, blk);
        gemm_kernel<<<dim3(12, 128), blkd, 0, stream>>>(Hb, Wf2, 0, C, bf2, 0, X, 0, B * L, C, 4 * C, 1, 0, blk);

        f32_to_out<<<(NX + 255) / 256, blkd, 0, stream>>>(X, d_out, 0, NX, blk);
    } else if (tierB) {
        float* X  = (float*)(ws + 64);
        u16*   XN = (u16*)(ws + 64 + 25165824);
        char*  P  = ws + 64 + 25165824 + 1572864;
        u16* Qb   = (u16*)P;
        u16* KVb  = (u16*)(P + 1572864);
        u16* AOb  = (u16*)(P + 4718592);
        u16* CNb  = (u16*)P;
        u16* KV2b = (u16*)(P + 786432);
        u16* Q2b  = (u16*)(P + 2359296);
        u16* AO2b = (u16*)(P + 3932160);
        u16* Hb   = (u16*)P;

        wire_to_f32<<<(NX + 255) / 256, blkd, 0, stream>>>(x, 0, X, NX, blk);

        for (int b = 0; b < B; b++) {
            size_t ro = (size_t)b * RL;
            ln_kernel<<<L, blkd, 0, stream>>>(X, ro, 0, g1, b1, XN, blk);
            gemm_kernel<<<dim3(12, 16), blkd, 0, stream>>>(XN, Wq1, 0, C, nullptr, 0, Qb, 0, L, C, C, 0, 1, blk);
            gemm_kernel<<<dim3(24, 16), blkd, 0, stream>>>(XN, Wkv1, 0, 2 * C, nullptr, 0, KVb, 0, L, 2 * C, C, 0, 1, blk);
            attn_kernel<<<dim3(64, 8), blkd, 0, stream>>>(Qb, KVb, KVb + C, AOb, C, 2 * C, 2 * C, C, 0, 0, 0, blk, b, L, 1);
            gemm_kernel<<<dim3(12, 16), blkd, 0, stream>>>(AOb, Wo1, 0, C, bo1, 0, X, ro, L, C, C, 1, 0, blk);

            ln_kernel<<<L, blkd, 0, stream>>>(X, ro, 0, g2, b2, XN, blk);
            ln_kernel<<<S, blkd, 0, stream>>>(c, (size_t)b * RS, 2, gc, bc, CNb, blk);
            gemm_kernel<<<dim3(24, 8), blkd, 0, stream>>>(CNb, Wkv2, 0, 2 * C, nullptr, 0, KV2b, 0, S, 2 * C, C, 0, 1, blk);
            gemm_kernel<<<dim3(12, 16), blkd, 0, stream>>>(XN, Wq2, 0, C, nullptr, 0, Q2b, 0, L, C, C, 0, 1, blk);
            attn_kernel<<<dim3(64, 8), blkd, 0, stream>>>(Q2b, KV2b, KV2b + C, AO2b, C, 2 * C, 2 * C, C, 0, 0, 0, blk, b, S, 0);
            gemm_kernel<<<dim3(12, 16), blkd, 0, stream>>>(AO2b, Wo2, 0, C, bo2, 0, X, ro, L, C, C, 1, 0, blk);

            ln_kernel<<<L, blkd, 0, stream>>>(X, ro, 0, g4, b4, XN, blk);
            gemm_kernel<<<dim3(48, 16), blkd, 0, stream>>>(XN, Wf1, 0, 4 * C, bf1, 0, Hb, 0, L, 4 * C, C, 1 | 2, 1, blk);
            gemm_kernel<<<dim3(12, 16), blkd, 0, stream>>>(Hb, Wf2, 0, C, bf2, 0, X, ro, L, C, 4 * C, 1, 0, blk);
        }
        f32_to_out<<<(NX + 255) / 256, blkd, 0, stream>>>(X, d_out, 0, NX, blk);
    } else {
        u16*  XN  = (u16*)(ws + 64);
        u16*  CNb = (u16*)(ws + 64 + 1572864);
        char* P2  = ws + 64 + 1572864 + 786432;
        u16* Qp  = (u16*)P2;
        u16* Kp  = (u16*)(P2 + 393216);
        u16* Vp  = (u16*)(P2 + 786432);
        u16* AOp = (u16*)(P2 + 1179648);
        u16* Hc  = (u16*)P2;

        wire_copy<<<(NX + 255) / 256, blkd, 0, stream>>>(x, d_out, NX, blk);

        for (int b = 0; b < B; b++) {
            size_t ro = (size_t)b * RL;

            ln_kernel<<<L, blkd, 0, stream>>>(d_out, ro, 2, g1, b1, XN, blk);
            for (int p = 0; p < 4; p++) {
                int h = 2 * p;
                gemm_kernel<<<dim3(3, 16), blkd, 0, stream>>>(XN, Wq1, (size_t)h * 96, C, nullptr, 0, Qp, 0, L, 192, C, 0, 1, blk);
                gemm_kernel<<<dim3(3, 16), blkd, 0, stream>>>(XN, Wkv1, (size_t)h * 96, 2 * C, nullptr, 0, Kp, 0, L, 192, C, 0, 1, blk);
                gemm_kernel<<<dim3(3, 16), blkd, 0, stream>>>(XN, Wkv1, (size_t)(C + h * 96), 2 * C, nullptr, 0, Vp, 0, L, 192, C, 0, 1, blk);
                attn_kernel<<<dim3(64, 2), blkd, 0, stream>>>(Qp, Kp, Vp, AOp, 192, 192, 192, 192, 0, 0, 0, blk, b, L, 1);
                gemm_kernel<<<dim3(12, 16), blkd, 0, stream>>>(AOp, Wo1, (size_t)h * 96 * C, C, bo1, 0, d_out, ro, L, C, 192, (p == 0) ? 1 : 0, 3, blk);
            }
            ln_kernel<<<L, blkd, 0, stream>>>(d_out, ro, 2, g2, b2, XN, blk);
            ln_kernel<<<S, blkd, 0, stream>>>(c, (size_t)b * RS, 2, gc, bc, CNb, blk);
            for (int p = 0; p < 4; p++) {
                int h = 2 * p;
                gemm_kernel<<<dim3(3, 16), blkd, 0, stream>>>(XN, Wq2, (size_t)h * 96, C, nullptr, 0, Qp, 0, L, 192, C, 0, 1, blk);
                gemm_kernel<<<dim3(3, 8), blkd, 0, stream>>>(CNb, Wkv2, (size_t)h * 96, 2 * C, nullptr, 0, Kp, 0, S, 192, C, 0, 1, blk);
                gemm_kernel<<<dim3(3, 8), blkd, 0, stream>>>(CNb, Wkv2, (size_t)(C + h * 96), 2 * C, nullptr, 0, Vp, 0, S, 192, C, 0, 1, blk);
                attn_kernel<<<dim3(64, 2), blkd, 0, stream>>>(Qp, Kp, Vp, AOp, 192, 192, 192, 192, 0, 0, 0, blk, b, S, 0);
                gemm_kernel<<<dim3(12, 16), blkd, 0, stream>>>(AOp, Wo2, (size_t)h * 96 * C, C, bo2, 0, d_out, ro, L, C, 192, (p == 0) ? 1 : 0, 3, blk);
            }
            ln_kernel<<<L, blkd, 0, stream>>>(d_out, ro, 2, g4, b4, XN, blk);
            for (int ch = 0; ch < 4; ch++) {
                gemm_kernel<<<dim3(12, 16), blkd, 0, stream>>>(XN, Wf1, (size_t)ch * C, 4 * C, bf1, ch * C, Hc, 0, L, C, C, 1 | 2, 1, blk);
                gemm_kernel<<<dim3(12, 16), blkd, 0, stream>>>(Hc, Wf2, (size_t)ch * C * C, C, bf2, 0, d_out, ro, L, C, C, (ch == 0) ? 1 : 0, 3, blk);
            }
        }
    }
}